// Round 1
// baseline (94.219 us; speedup 1.0000x reference)
//
#include <hip/hip_runtime.h>
#include <math.h>

#define BN_EPS 1e-5f

// Problem geometry (derived at runtime, tiles assume divisibility: B%128==0, O%32==0, I%64==0)
constexpr int BT  = 128;  // batch rows per block
constexpr int OT  = 32;   // out-features per block
constexpr int IC  = 64;   // in-feature chunk staged in LDS
constexpr int TPB = 512;  // threads per block (8 waves)
constexpr int PAD = 4;    // LDS row padding (floats) to break bank conflicts
constexpr int LDR = IC + PAD;  // 68 floats = 272B row stride (16B aligned)

__device__ __forceinline__ float fast_exp2(float a) {
#if __has_builtin(__builtin_amdgcn_exp2f)
    return __builtin_amdgcn_exp2f(a);
#else
    return __expf(a * 0.6931471805599453f);
#endif
}

// cos(2*pi*r)
__device__ __forceinline__ float fast_cosrev(float r) {
#if __has_builtin(__builtin_amdgcn_fractf)
    r = __builtin_amdgcn_fractf(r);
#else
    r = r - floorf(r);
#endif
#if __has_builtin(__builtin_amdgcn_cosf)
    return __builtin_amdgcn_cosf(r);
#else
    return __cosf(r * 6.283185307179586f);
#endif
}

// K1: y[b,o] = sum_i cos(5u)*exp(-0.5u^2)*w[o,i], u=(x-bias)/scale
// plus per-o partial sums of y and y^2 (atomically accumulated into gsum/gsq).
__global__ __launch_bounds__(TPB, 4)
void kan_forward(const float* __restrict__ x, const float* __restrict__ scale,
                 const float* __restrict__ bias, const float* __restrict__ weight,
                 float* __restrict__ y, float* __restrict__ gsum,
                 float* __restrict__ gsq, int B, int I, int O)
{
    __shared__ __align__(16) float xs[BT][LDR];  // x tile            34 KB
    __shared__ __align__(16) float pr[OT][LDR];  // 1/scale           8.5 KB
    __shared__ __align__(16) float pc[OT][LDR];  // -bias/scale       8.5 KB
    __shared__ __align__(16) float pw[OT][LDR];  // weight            8.5 KB

    const int tid = threadIdx.x;
    const int og  = tid & 15;   // o-group: this thread's o = og*2 + {0,1}
    const int bg  = tid >> 4;   // b-group: this thread's b = bg*4 + {0..3} (bg 0..31)
    const int O0  = blockIdx.x * OT;
    const int B0  = blockIdx.y * BT;

    const float KM = 0.84932181f;            // sqrt(0.5*log2(e)): exp(-u^2/2)=2^(-(u*KM)^2)
    const float KC = 5.0f * 0.15915494309189535f;  // omega0/(2*pi): revolutions

    float acc[4][2] = {{0.f,0.f},{0.f,0.f},{0.f,0.f},{0.f,0.f}};

    for (int ic = 0; ic < I; ic += IC) {
        __syncthreads();
        // stage x tile: BT*IC/4 = 2048 float4, 4 per thread
        for (int r = tid; r < BT * (IC/4); r += TPB) {
            const int row = r >> 4;            // / (IC/4)
            const int c4  = (r & 15) * 4;
            float4 v = *reinterpret_cast<const float4*>(&x[(size_t)(B0+row)*I + ic + c4]);
            *reinterpret_cast<float4*>(&xs[row][c4]) = v;
        }
        // stage params: OT*IC/4 = 512 float4 per array, 1 per thread
        for (int r = tid; r < OT * (IC/4); r += TPB) {
            const int row = r >> 4;
            const int c4  = (r & 15) * 4;
            const size_t g = (size_t)(O0+row)*I + ic + c4;
            float4 sv = *reinterpret_cast<const float4*>(&scale[g]);
            float4 bv = *reinterpret_cast<const float4*>(&bias[g]);
            float4 wv = *reinterpret_cast<const float4*>(&weight[g]);
            float4 rv, cv;
            rv.x = 1.0f/sv.x; rv.y = 1.0f/sv.y; rv.z = 1.0f/sv.z; rv.w = 1.0f/sv.w;
            cv.x = -bv.x*rv.x; cv.y = -bv.y*rv.y; cv.z = -bv.z*rv.z; cv.w = -bv.w*rv.w;
            *reinterpret_cast<float4*>(&pr[row][c4]) = rv;
            *reinterpret_cast<float4*>(&pc[row][c4]) = cv;
            *reinterpret_cast<float4*>(&pw[row][c4]) = wv;
        }
        __syncthreads();

        #pragma unroll 2
        for (int i = 0; i < IC; i += 4) {
            float4 xv[4];
            #pragma unroll
            for (int k = 0; k < 4; ++k)
                xv[k] = *reinterpret_cast<const float4*>(&xs[bg*4+k][i]);
            #pragma unroll
            for (int j = 0; j < 2; ++j) {
                const int o = og*2 + j;
                const float4 rv = *reinterpret_cast<const float4*>(&pr[o][i]);
                const float4 cv = *reinterpret_cast<const float4*>(&pc[o][i]);
                const float4 wv = *reinterpret_cast<const float4*>(&pw[o][i]);
                const float* rp = reinterpret_cast<const float*>(&rv);
                const float* cp = reinterpret_cast<const float*>(&cv);
                const float* wp = reinterpret_cast<const float*>(&wv);
                #pragma unroll
                for (int k = 0; k < 4; ++k) {
                    const float* xp = reinterpret_cast<const float*>(&xv[k]);
                    #pragma unroll
                    for (int e = 0; e < 4; ++e) {
                        const float u  = fmaf(xp[e], rp[e], cp[e]);
                        const float m  = u * KM;
                        const float ex = fast_exp2(-(m*m));
                        const float cs = fast_cosrev(u * KC);
                        acc[k][j] = fmaf(cs*ex, wp[e], acc[k][j]);
                    }
                }
            }
        }
    }

    // ---- write y (float2 per b-row: two consecutive o) ----
    #pragma unroll
    for (int k = 0; k < 4; ++k) {
        float2 v = make_float2(acc[k][0], acc[k][1]);
        *reinterpret_cast<float2*>(&y[(size_t)(B0 + bg*4 + k)*O + O0 + og*2]) = v;
    }

    // ---- per-o partial sums for batch-norm ----
    float s[2], q[2];
    #pragma unroll
    for (int j = 0; j < 2; ++j) {
        s[j] = acc[0][j]+acc[1][j]+acc[2][j]+acc[3][j];
        q[j] = acc[0][j]*acc[0][j]+acc[1][j]*acc[1][j]
             + acc[2][j]*acc[2][j]+acc[3][j]*acc[3][j];
        // reduce over the 4 b-groups within this wave (lane^16 -> bg^1, lane^32 -> bg^2)
        s[j] += __shfl_xor(s[j], 16); s[j] += __shfl_xor(s[j], 32);
        q[j] += __shfl_xor(q[j], 16); q[j] += __shfl_xor(q[j], 32);
    }
    __syncthreads();               // xs no longer needed; reuse as reduction scratch
    float* red = &xs[0][0];        // [0..255]: sums (8 waves x 32 o), [256..511]: sumsq
    const int wave = tid >> 6;
    const int lane = tid & 63;
    if (lane < 16) {
        red[      wave*32 + og*2 + 0] = s[0];
        red[      wave*32 + og*2 + 1] = s[1];
        red[256 + wave*32 + og*2 + 0] = q[0];
        red[256 + wave*32 + og*2 + 1] = q[1];
    }
    __syncthreads();
    if (tid < OT) {
        float ss = 0.f, qq = 0.f;
        #pragma unroll
        for (int w = 0; w < TPB/64; ++w) {
            ss += red[      w*32 + tid];
            qq += red[256 + w*32 + tid];
        }
        atomicAdd(&gsum[O0 + tid], ss);
        atomicAdd(&gsq [O0 + tid], qq);
    }
}

// K2: per-o affine coefficients a = gamma*rsqrt(var+eps), c = beta - mean*a
__global__ void bn_finalize(const float* __restrict__ gsum, const float* __restrict__ gsq,
                            const float* __restrict__ gamma, const float* __restrict__ beta,
                            float* __restrict__ A, float* __restrict__ C, int B, int O)
{
    const int o = blockIdx.x * blockDim.x + threadIdx.x;
    if (o >= O) return;
    const float invB = 1.0f / (float)B;
    const float m = gsum[o] * invB;
    const float v = fmaxf(gsq[o] * invB - m*m, 0.f);
    const float a = gamma[o] * rsqrtf(v + BN_EPS);
    A[o] = a;
    C[o] = fmaf(-m, a, beta[o]);
}

// K3: in-place out = y*a[o] + c[o]
__global__ __launch_bounds__(256)
void bn_apply(float* __restrict__ y, const float* __restrict__ A,
              const float* __restrict__ C, int O, int n4)
{
    const int p = blockIdx.x * blockDim.x + threadIdx.x;
    if (p >= n4) return;
    float4 v = reinterpret_cast<float4*>(y)[p];
    const int o = (p*4) % O;   // O is a multiple of 4
    float4 r;
    r.x = fmaf(v.x, A[o+0], C[o+0]);
    r.y = fmaf(v.y, A[o+1], C[o+1]);
    r.z = fmaf(v.z, A[o+2], C[o+2]);
    r.w = fmaf(v.w, A[o+3], C[o+3]);
    reinterpret_cast<float4*>(y)[p] = r;
}

extern "C" void kernel_launch(void* const* d_in, const int* in_sizes, int n_in,
                              void* d_out, int out_size, void* d_ws, size_t ws_size,
                              hipStream_t stream)
{
    const float* x      = (const float*)d_in[0];
    const float* scale  = (const float*)d_in[1];
    const float* bias   = (const float*)d_in[2];
    const float* weight = (const float*)d_in[3];
    const float* gamma  = (const float*)d_in[4];
    const float* beta   = (const float*)d_in[5];
    float* y = (float*)d_out;

    const int O = in_sizes[4];            // gamma: (O,)
    const int I = in_sizes[1] / O;        // scale: (O,I)
    const int B = in_sizes[0] / I;        // x: (B,I)

    float* gsum = (float*)d_ws;           // [O]
    float* gsq  = gsum + O;               // [O]
    float* A    = gsq  + O;               // [O]
    float* C    = A    + O;               // [O]

    hipMemsetAsync(d_ws, 0, (size_t)2 * O * sizeof(float), stream);

    dim3 grid(O / OT, B / BT);
    kan_forward<<<grid, TPB, 0, stream>>>(x, scale, bias, weight, y, gsum, gsq, B, I, O);

    bn_finalize<<<(O + 255)/256, 256, 0, stream>>>(gsum, gsq, gamma, beta, A, C, B, O);

    const int n4 = (B * O) / 4;
    bn_apply<<<(n4 + 255)/256, 256, 0, stream>>>(y, A, C, O, n4);
}